// Round 4
// baseline (286.944 us; speedup 1.0000x reference)
//
#include <hip/hip_runtime.h>

#define BATCH 8
#define SEQL 16384
#define NCH 128
#define NH 4
#define HD 32
#define GEPS 1e-5f

typedef __bf16 bf16x8 __attribute__((ext_vector_type(8)));
typedef __bf16 bf16x4 __attribute__((ext_vector_type(4)));
typedef float f32x4 __attribute__((ext_vector_type(4)));

// ---- workspace byte offsets ----
#define WKV_B   0                      // 256*128 bf16 [o'][c], o'=o-128 (k:0..127, v:128..255)
#define WQ_B    65536                  // 128*128 bf16 [o][c]
#define WO_B    98304                  // 128*128 bf16 [o][c]
#define CTXB_B  131072                 // 8*4*32*32 bf16 = 64 KiB, [b][h][c][d]
#define CTXP_B  196608                 // 1024 blk * 4 h * 32 d * 32 c bf16 = 8 MiB
#define ZP_B    (196608 + 8388608)     // 1024 blk * 4 w * 128 f32 = 2 MiB
#define GNS_B   (ZP_B + 2097152)       // 8*2 f32
#define GNF_B   (GNS_B + 64)           // 8*2 f32

__global__ void k_prep(const float* __restrict__ wqkv, const float* __restrict__ wout,
                       char* __restrict__ wsb) {
    int i = blockIdx.x * 256 + threadIdx.x;
    __bf16* wkvb = (__bf16*)(wsb + WKV_B);
    __bf16* wqb  = (__bf16*)(wsb + WQ_B);
    __bf16* wob  = (__bf16*)(wsb + WO_B);
    if (i < 384 * 128) {
        int o = i >> 7, c = i & 127;
        __bf16 v = (__bf16)wqkv[i];
        if (o < 128) wqb[o * 128 + c] = v;
        else         wkvb[(o - 128) * 128 + c] = v;
    }
    if (i < 128 * 128) wob[i] = (__bf16)wout[i];
}

// Pass 1: kv = x @ Wkv^T per 64-token tile (A = x direct from global, B = Wkv streamed),
// ek = exp(k) -> ekv LDS [o][t] (b64 writes); ctx += ek (outer) v via MFMA;
// per-block bf16 ctx partials + f32 Z partials (no atomics).
__global__ __launch_bounds__(256, 4) void k_pass1(const float* __restrict__ x,
                                                  char* __restrict__ wsb) {
    __shared__ __attribute__((aligned(16))) __bf16 ekv[256 * 68];   // [o 256][t 64 +4 pad]
    const int t = threadIdx.x;
    const int lane = t & 63, wave = t >> 6;
    const int n16 = lane & 15, q = lane >> 4;
    const int blk = blockIdx.x;
    const int batch = blk >> 7, sub = blk & 127;
    const __bf16* __restrict__ wkvb = (const __bf16*)(wsb + WKV_B);

    f32x4 ctxacc[2][2];
#pragma unroll
    for (int i = 0; i < 2; i++)
#pragma unroll
        for (int j = 0; j < 2; j++) ctxacc[i][j] = (f32x4){0.f, 0.f, 0.f, 0.f};
    float zacc[8];
#pragma unroll
    for (int j = 0; j < 8; j++) zacc[j] = 0.f;

    // prefetch rep0 x: this lane's A-row (token = tok0 + wave*16 + n16), all 128 ch
    float4 px[8];
    {
        const float* xr = x + ((size_t)(batch * SEQL + sub * 64) + wave * 16 + n16) * NCH;
#pragma unroll
        for (int ks = 0; ks < 4; ks++) {
            px[2 * ks]     = *(const float4*)&xr[ks * 32 + q * 8];
            px[2 * ks + 1] = *(const float4*)&xr[ks * 32 + q * 8 + 4];
        }
    }

    for (int rep = 0; rep < 2; rep++) {
        // convert prefetched x to A-fragments
        bf16x8 ax[4];
#pragma unroll
        for (int ks = 0; ks < 4; ks++) {
            bf16x8 a;
            a[0] = (__bf16)px[2 * ks].x;     a[1] = (__bf16)px[2 * ks].y;
            a[2] = (__bf16)px[2 * ks].z;     a[3] = (__bf16)px[2 * ks].w;
            a[4] = (__bf16)px[2 * ks + 1].x; a[5] = (__bf16)px[2 * ks + 1].y;
            a[6] = (__bf16)px[2 * ks + 1].z; a[7] = (__bf16)px[2 * ks + 1].w;
            ax[ks] = a;
        }
        // KV GEMM in two halves of 8 o-tiles (half0 = k channels, half1 = v)
#pragma unroll
        for (int half = 0; half < 2; half++) {
            f32x4 acc[8];
#pragma unroll
            for (int j = 0; j < 8; j++) acc[j] = (f32x4){0.f, 0.f, 0.f, 0.f};
#pragma unroll
            for (int ks = 0; ks < 4; ks++) {
#pragma unroll
                for (int j = 0; j < 8; j++) {
                    int o = (half * 8 + j) * 16 + n16;
                    bf16x8 bw = *(const bf16x8*)&wkvb[o * 128 + ks * 32 + q * 8];
                    acc[j] = __builtin_amdgcn_mfma_f32_16x16x32_bf16(ax[ks], bw, acc[j], 0, 0, 0);
                }
            }
            // exp (k half), Z accumulate, b64 LDS write in [o][t] layout
#pragma unroll
            for (int j = 0; j < 8; j++) {
                int o = (half * 8 + j) * 16 + n16;
                f32x4 v = acc[j];
                if (half == 0) {
                    v[0] = __expf(v[0]); v[1] = __expf(v[1]);
                    v[2] = __expf(v[2]); v[3] = __expf(v[3]);
                    zacc[j] += v[0] + v[1] + v[2] + v[3];
                }
                bf16x4 hh;
                hh.x = (__bf16)v[0]; hh.y = (__bf16)v[1];
                hh.z = (__bf16)v[2]; hh.w = (__bf16)v[3];
                *(bf16x4*)&ekv[o * 68 + wave * 16 + q * 4] = hh;
            }
        }
        // prefetch rep1 x while ctx phase runs
        if (rep == 0) {
            const float* xr = x + ((size_t)(batch * SEQL + (sub + 128) * 64) + wave * 16 + n16) * NCH;
#pragma unroll
            for (int ks = 0; ks < 4; ks++) {
                px[2 * ks]     = *(const float4*)&xr[ks * 32 + q * 8];
                px[2 * ks + 1] = *(const float4*)&xr[ks * 32 + q * 8 + 4];
            }
        }
        __syncthreads();
        // ctx MFMA: wave = head h; A = ek[c][t], B = v[d][t]; k = 64 tokens (2 steps)
#pragma unroll
        for (int ks2 = 0; ks2 < 2; ks2++) {
            bf16x8 ea[2], vb[2];
#pragma unroll
            for (int ml = 0; ml < 2; ml++) {
                ea[ml] = *(const bf16x8*)&ekv[(wave * 32 + ml * 16 + n16) * 68 + ks2 * 32 + q * 8];
                vb[ml] = *(const bf16x8*)&ekv[(128 + wave * 32 + ml * 16 + n16) * 68 + ks2 * 32 + q * 8];
            }
#pragma unroll
            for (int ml = 0; ml < 2; ml++)
#pragma unroll
                for (int nl = 0; nl < 2; nl++)
                    ctxacc[ml][nl] = __builtin_amdgcn_mfma_f32_16x16x32_bf16(
                        ea[ml], vb[nl], ctxacc[ml][nl], 0, 0, 0);
        }
        if (rep == 0) __syncthreads();
    }
    // ctx partial store: lane holds D[c = ml*16+q*4+r][d = nl*16+n16]; layout [d][c] bf16
    __bf16* ctxp = (__bf16*)(wsb + CTXP_B) + ((size_t)blk * 4 + wave) * 1024;
#pragma unroll
    for (int ml = 0; ml < 2; ml++)
#pragma unroll
        for (int nl = 0; nl < 2; nl++) {
            bf16x4 hh;
            hh.x = (__bf16)ctxacc[ml][nl][0]; hh.y = (__bf16)ctxacc[ml][nl][1];
            hh.z = (__bf16)ctxacc[ml][nl][2]; hh.w = (__bf16)ctxacc[ml][nl][3];
            *(bf16x4*)&ctxp[(nl * 16 + n16) * 32 + ml * 16 + q * 4] = hh;
        }
    // Z partial: butterfly over q, one f32 row of 128 per wave
    float* zp = (float*)(wsb + ZP_B) + ((size_t)blk * 4 + wave) * 128;
#pragma unroll
    for (int j = 0; j < 8; j++) {
        float z = zacc[j];
        z += __shfl_xor(z, 16);
        z += __shfl_xor(z, 32);
        if (q == 0) zp[j * 16 + n16] = z;
    }
}

// Reduce: per (batch, head): Z = sum of Z partials; ctx[c][d] = (sum of partials)/Z[c] -> bf16
__global__ __launch_bounds__(256) void k_reduce(char* __restrict__ wsb) {
    __shared__ float zpart[8][32];
    __shared__ float zs[32];
    const int t = threadIdx.x;
    const int b = blockIdx.x >> 2, h = blockIdx.x & 3;
    const float* zp = (const float*)(wsb + ZP_B);
    {
        int c = t & 31, g = t >> 5;
        float s = 0.f;
        for (int s8 = g; s8 < 128; s8 += 8)
#pragma unroll
            for (int w = 0; w < 4; w++)
                s += zp[((size_t)(b * 128 + s8) * 4 + w) * 128 + h * 32 + c];
        zpart[g][c] = s;
    }
    __syncthreads();
    if (t < 32) {
        float s = 0.f;
#pragma unroll
        for (int g = 0; g < 8; g++) s += zpart[g][t];
        zs[t] = s;
    }
    __syncthreads();
    // ctx partials: layout per (blk,h): [d 32][c 32] bf16; thread owns 4 consecutive c at one d
    const __bf16* ctxp = (const __bf16*)(wsb + CTXP_B);
    float s0 = 0.f, s1 = 0.f, s2 = 0.f, s3 = 0.f;
    size_t base = ((size_t)(b * 512 + h)) * 1024 + t * 4;
    for (int sub = 0; sub < 128; sub++) {
        bf16x4 v = *(const bf16x4*)&ctxp[base + (size_t)sub * 4096];
        s0 += (float)v.x; s1 += (float)v.y; s2 += (float)v.z; s3 += (float)v.w;
    }
    int d = t >> 3, c0 = (t & 7) * 4;
    __bf16* ctxb = (__bf16*)(wsb + CTXB_B) + (size_t)(b * 4 + h) * 1024;
    ctxb[(c0 + 0) * 32 + d] = (__bf16)(s0 / zs[c0 + 0]);
    ctxb[(c0 + 1) * 32 + d] = (__bf16)(s1 / zs[c0 + 1]);
    ctxb[(c0 + 2) * 32 + d] = (__bf16)(s2 / zs[c0 + 2]);
    ctxb[(c0 + 3) * 32 + d] = (__bf16)(s3 / zs[c0 + 3]);
}

// Pass 2: q = Wq @ x (MFMA); softmax over head-dim in registers; attn = ctx @ p (MFMA);
// out = Wout @ attn + bias (MFMA); GN partial sums; store pre-GN out.
__global__ __launch_bounds__(256, 4) void k_pass2(const float* __restrict__ x,
                                                  const float* __restrict__ bout,
                                                  char* __restrict__ wsb,
                                                  float* __restrict__ out) {
    __shared__ __attribute__((aligned(16))) __bf16 bufA[8352];
    __shared__ __attribute__((aligned(16))) __bf16 bufB[8352];
    __shared__ float gred[8];
    const int t = threadIdx.x;
    const int lane = t & 63, wave = t >> 6;       // wave == head h
    const int n16 = lane & 15, q = lane >> 4;
    const int batch = blockIdx.x >> 8, chunk = blockIdx.x & 255;
    const __bf16* __restrict__ wqb = (const __bf16*)(wsb + WQ_B);
    const __bf16* __restrict__ wob = (const __bf16*)(wsb + WO_B);
    const __bf16* __restrict__ ctxb = (const __bf16*)(wsb + CTXB_B);

    const size_t tok0 = (size_t)batch * SEQL + chunk * 64;
    const float* xg = x + tok0 * NCH;
#pragma unroll
    for (int r = 0; r < 8; r++) {
        int e = t + r * 256;
        int tok = e >> 5, c4 = (e & 31) * 4;
        float4 v = ((const float4*)xg)[e];
        bf16x4 h; h.x = (__bf16)v.x; h.y = (__bf16)v.y; h.z = (__bf16)v.z; h.w = (__bf16)v.w;
        *(bf16x4*)&bufA[(c4 >> 5) * 2088 + ((c4 >> 3) & 3) * 520 + tok * 8 + (c4 & 7)] = h;
    }
    bf16x8 aq[2][4];
#pragma unroll
    for (int ml = 0; ml < 2; ml++)
#pragma unroll
        for (int ks = 0; ks < 4; ks++)
            aq[ml][ks] = *(const bf16x8*)&wqb[(wave * 32 + ml * 16 + n16) * 128 + ks * 32 + q * 8];
    bf16x8 actx[2];
#pragma unroll
    for (int ml = 0; ml < 2; ml++)
        actx[ml] = *(const bf16x8*)&ctxb[((size_t)(batch * 4 + wave) * 32 + ml * 16 + n16) * 32 + q * 8];
    __syncthreads();

    f32x4 qacc[2][4];
#pragma unroll
    for (int i = 0; i < 2; i++)
#pragma unroll
        for (int j = 0; j < 4; j++) qacc[i][j] = (f32x4){0.f, 0.f, 0.f, 0.f};
#pragma unroll
    for (int ks = 0; ks < 4; ks++) {
        bf16x8 b[4];
#pragma unroll
        for (int nt = 0; nt < 4; nt++)
            b[nt] = *(const bf16x8*)&bufA[ks * 2088 + q * 520 + (nt * 16 + n16) * 8];
#pragma unroll
        for (int ml = 0; ml < 2; ml++)
#pragma unroll
            for (int nt = 0; nt < 4; nt++)
                qacc[ml][nt] = __builtin_amdgcn_mfma_f32_16x16x32_bf16(
                    aq[ml][ks], b[nt], qacc[ml][nt], 0, 0, 0);
    }
#pragma unroll
    for (int nt = 0; nt < 4; nt++) {
        float ss = 0.f;
#pragma unroll
        for (int ml = 0; ml < 2; ml++)
#pragma unroll
            for (int r = 0; r < 4; r++) {
                float e = __expf(qacc[ml][nt][r]);
                qacc[ml][nt][r] = e;
                ss += e;
            }
        ss += __shfl_xor(ss, 16);
        ss += __shfl_xor(ss, 32);
        float inv = 0.17677669529663687f / ss;   // (1/sqrt(32)) / denom
#pragma unroll
        for (int ml = 0; ml < 2; ml++)
#pragma unroll
            for (int r = 0; r < 4; r++) qacc[ml][nt][r] *= inv;
    }
    __syncthreads();   // all waves done reading bufA (x)
#pragma unroll
    for (int ml = 0; ml < 2; ml++)
#pragma unroll
        for (int nt = 0; nt < 4; nt++) {
            bf16x4 h;
            h.x = (__bf16)qacc[ml][nt][0]; h.y = (__bf16)qacc[ml][nt][1];
            h.z = (__bf16)qacc[ml][nt][2]; h.w = (__bf16)qacc[ml][nt][3];
            *(bf16x4*)&bufB[wave * 2088 + (ml * 2 + (q >> 1)) * 520 +
                            (nt * 16 + n16) * 8 + (q & 1) * 4] = h;
        }
    __builtin_amdgcn_fence(__ATOMIC_ACQ_REL, "workgroup");  // wave-private round trip
#pragma unroll
    for (int ml = 0; ml < 2; ml++)
#pragma unroll
        for (int nt = 0; nt < 4; nt++) {
            bf16x8 pb = *(const bf16x8*)&bufB[wave * 2088 + q * 520 + (nt * 16 + n16) * 8];
            f32x4 aacc = __builtin_amdgcn_mfma_f32_16x16x32_bf16(
                actx[ml], pb, (f32x4){0.f, 0.f, 0.f, 0.f}, 0, 0, 0);
            bf16x4 h;
            h.x = (__bf16)aacc[0]; h.y = (__bf16)aacc[1];
            h.z = (__bf16)aacc[2]; h.w = (__bf16)aacc[3];
            *(bf16x4*)&bufA[wave * 2088 + (ml * 2 + (q >> 1)) * 520 +
                            (nt * 16 + n16) * 8 + (q & 1) * 4] = h;
        }
    __syncthreads();
    f32x4 oacc[2][4];
#pragma unroll
    for (int i = 0; i < 2; i++)
#pragma unroll
        for (int j = 0; j < 4; j++) oacc[i][j] = (f32x4){0.f, 0.f, 0.f, 0.f};
#pragma unroll
    for (int ks = 0; ks < 4; ks++) {
        bf16x8 ao  = *(const bf16x8*)&wob[(wave * 32 + n16) * 128 + ks * 32 + q * 8];
        bf16x8 ao1 = *(const bf16x8*)&wob[(wave * 32 + 16 + n16) * 128 + ks * 32 + q * 8];
        bf16x8 b[4];
#pragma unroll
        for (int nt = 0; nt < 4; nt++)
            b[nt] = *(const bf16x8*)&bufA[ks * 2088 + q * 520 + (nt * 16 + n16) * 8];
#pragma unroll
        for (int nt = 0; nt < 4; nt++) {
            oacc[0][nt] = __builtin_amdgcn_mfma_f32_16x16x32_bf16(ao, b[nt], oacc[0][nt], 0, 0, 0);
            oacc[1][nt] = __builtin_amdgcn_mfma_f32_16x16x32_bf16(ao1, b[nt], oacc[1][nt], 0, 0, 0);
        }
    }
    float4 bias[2];
#pragma unroll
    for (int ml = 0; ml < 2; ml++)
        bias[ml] = *(const float4*)&bout[wave * 32 + ml * 16 + q * 4];
    float s1 = 0.f, s2 = 0.f;
#pragma unroll
    for (int ml = 0; ml < 2; ml++)
#pragma unroll
        for (int nt = 0; nt < 4; nt++) {
            float4 vv;
            vv.x = oacc[ml][nt][0] + bias[ml].x;
            vv.y = oacc[ml][nt][1] + bias[ml].y;
            vv.z = oacc[ml][nt][2] + bias[ml].z;
            vv.w = oacc[ml][nt][3] + bias[ml].w;
            s1 += vv.x + vv.y + vv.z + vv.w;
            s2 += vv.x * vv.x + vv.y * vv.y + vv.z * vv.z + vv.w * vv.w;
            *(float4*)&out[(tok0 + nt * 16 + n16) * NCH + wave * 32 + ml * 16 + q * 4] = vv;
        }
#pragma unroll
    for (int off = 32; off > 0; off >>= 1) {
        s1 += __shfl_xor(s1, off);
        s2 += __shfl_xor(s2, off);
    }
    if (lane == 0) { gred[wave] = s1; gred[4 + wave] = s2; }
    __syncthreads();
    if (t == 0) {
        float* gns = (float*)(wsb + GNS_B);
        atomicAdd(&gns[batch * 2 + 0], gred[0] + gred[1] + gred[2] + gred[3]);
        atomicAdd(&gns[batch * 2 + 1], gred[4] + gred[5] + gred[6] + gred[7]);
    }
}

__global__ void k_gnfinal(char* __restrict__ wsb) {
    int b = threadIdx.x;
    if (b < BATCH) {
        const float n = (float)NCH * (float)SEQL;
        const float* gns = (const float*)(wsb + GNS_B);
        float* gnf = (float*)(wsb + GNF_B);
        float mean = gns[b * 2] / n;
        float var = gns[b * 2 + 1] / n - mean * mean;
        gnf[b * 2] = mean;
        gnf[b * 2 + 1] = rsqrtf(var + GEPS);
    }
}

__global__ __launch_bounds__(256) void k_gnorm(float* __restrict__ out,
                                               const char* __restrict__ wsb,
                                               const float* __restrict__ gw,
                                               const float* __restrict__ gb) {
    size_t i4 = (size_t)blockIdx.x * 256 + threadIdx.x;
    int b = (int)(i4 >> 19);
    int c4 = (int)(i4 & 31);
    const float* gnf = (const float*)(wsb + GNF_B);
    float mean = gnf[b * 2], rstd = gnf[b * 2 + 1];
    float4 w = *(const float4*)&gw[c4 * 4];
    float4 bb = *(const float4*)&gb[c4 * 4];
    float4 v = ((float4*)out)[i4];
    v.x = (v.x - mean) * rstd * w.x + bb.x;
    v.y = (v.y - mean) * rstd * w.y + bb.y;
    v.z = (v.z - mean) * rstd * w.z + bb.z;
    v.w = (v.w - mean) * rstd * w.w + bb.w;
    ((float4*)out)[i4] = v;
}

extern "C" void kernel_launch(void* const* d_in, const int* in_sizes, int n_in,
                              void* d_out, int out_size, void* d_ws, size_t ws_size,
                              hipStream_t stream) {
    const float* x    = (const float*)d_in[0];
    const float* wqkv = (const float*)d_in[1];
    const float* wout = (const float*)d_in[2];
    const float* bout = (const float*)d_in[3];
    const float* gw   = (const float*)d_in[4];
    const float* gb   = (const float*)d_in[5];
    float* out = (float*)d_out;
    char* wsb  = (char*)d_ws;

    hipMemsetAsync(wsb + GNS_B, 0, 64, stream);
    k_prep<<<192, 256, 0, stream>>>(wqkv, wout, wsb);
    k_pass1<<<1024, 256, 0, stream>>>(x, wsb);
    k_reduce<<<32, 256, 0, stream>>>(wsb);
    k_pass2<<<2048, 256, 0, stream>>>(x, bout, wsb, out);
    k_gnfinal<<<1, 64, 0, stream>>>(wsb);
    k_gnorm<<<16384, 256, 0, stream>>>(out, wsb, gw, gb);
}